// Round 1
// baseline (170.918 us; speedup 1.0000x reference)
//
#include <hip/hip_runtime.h>

#define BH 32
#define L  1024
#define D  64
#define PAD 72   // ushort stride: 144 B -> rows advance 4 banks, conflict-free b128 reads

typedef __bf16 bf16x8  __attribute__((ext_vector_type(8)));
typedef float  f32x16  __attribute__((ext_vector_type(16)));

__device__ __forceinline__ unsigned short f2bf(float f) {
    union { float f; unsigned u; } v; v.f = f;
    unsigned r = v.u + 0x7fffu + ((v.u >> 16) & 1u);   // RNE
    return (unsigned short)(r >> 16);
}

// ---------------------------------------------------------------------------
// Fully fused: per block (128x128 output tile of one bh):
//   1. stage W1 (64x64), X rows i0..i0+127, Y rows j0..j0+127 as bf16 in LDS
//   2. per-wave in-place projection: Xf = (X@W1^T + b1)*w2, Yf = Y@W1^T + b1
//      (each wave owns a disjoint 32-row stripe; raw reads are consumed into
//       registers before the write-back, so no extra barrier needed)
//   3. 128x128 TN score GEMM from LDS, relu, coalesced dword stores
// ---------------------------------------------------------------------------
__global__ __launch_bounds__(256, 3) void fused_kernel(
    const float* __restrict__ X, const float* __restrict__ Y,
    const float* __restrict__ W1, const float* __restrict__ b1,
    const float* __restrict__ w2, const float* __restrict__ b2p,
    float* __restrict__ out)
{
    __shared__ unsigned short Wl[64 * PAD];    //  9 KiB
    __shared__ unsigned short As[128 * PAD];   // 18 KiB
    __shared__ unsigned short Bs[128 * PAD];   // 18 KiB  -> 45 KiB total, 3 blk/CU

    const int tid = threadIdx.x;
    const int bh  = blockIdx.z;
    const int i0  = blockIdx.y * 128;
    const int j0  = blockIdx.x * 128;

    // ---- stage W1 (64x64 fp32 -> bf16) ----
    {
        const int d  = tid >> 2;
        const int kb = (tid & 3) * 16;
        const float4* wp = (const float4*)(W1 + d * 64 + kb);
        #pragma unroll
        for (int q = 0; q < 4; ++q) {
            float4 v = wp[q];
            unsigned short* o = &Wl[d * PAD + kb + q * 4];
            o[0] = f2bf(v.x); o[1] = f2bf(v.y); o[2] = f2bf(v.z); o[3] = f2bf(v.w);
        }
    }
    // ---- stage X tile and Y tile (each 128x64 fp32 = 32 KiB, contiguous) ----
    {
        const float4* xp = (const float4*)(X + ((size_t)bh * L + i0) * D);
        const float4* yp = (const float4*)(Y + ((size_t)bh * L + j0) * D);
        #pragma unroll
        for (int p = 0; p < 8; ++p) {
            int c   = tid + 256 * p;          // float4 chunk 0..2047
            int row = c >> 4;                 // 16 float4 per 64-elem row
            int c4  = (c & 15) * 4;
            float4 vx = xp[c];
            float4 vy = yp[c];
            unsigned short* ox = &As[row * PAD + c4];
            ox[0] = f2bf(vx.x); ox[1] = f2bf(vx.y); ox[2] = f2bf(vx.z); ox[3] = f2bf(vx.w);
            unsigned short* oy = &Bs[row * PAD + c4];
            oy[0] = f2bf(vy.x); oy[1] = f2bf(vy.y); oy[2] = f2bf(vy.z); oy[3] = f2bf(vy.w);
        }
    }
    __syncthreads();

    const int w   = tid >> 6;                 // wave 0..3
    const int l   = tid & 63;
    const int l31 = l & 31;
    const int lh  = l >> 5;

    // ---- projection, in place: wave w owns rows [w*32, w*32+32) ----
    {
        const int arow = w * 32 + l31;
        bf16x8 ax[4], ay[4];
        #pragma unroll
        for (int kk = 0; kk < 4; ++kk) {
            int k0 = kk * 16 + lh * 8;
            ax[kk] = *(const bf16x8*)&As[arow * PAD + k0];
            ay[kk] = *(const bf16x8*)&Bs[arow * PAD + k0];
        }
        f32x16 accx[2] = {};
        f32x16 accy[2] = {};
        #pragma unroll
        for (int kk = 0; kk < 4; ++kk) {
            int k0 = kk * 16 + lh * 8;
            #pragma unroll
            for (int nt = 0; nt < 2; ++nt) {
                bf16x8 wv = *(const bf16x8*)&Wl[(nt * 32 + l31) * PAD + k0];
                accx[nt] = __builtin_amdgcn_mfma_f32_32x32x16_bf16(ax[kk], wv, accx[nt], 0, 0, 0);
                accy[nt] = __builtin_amdgcn_mfma_f32_32x32x16_bf16(ay[kk], wv, accy[nt], 0, 0, 0);
            }
        }
        // write back into the wave's own stripe (reads already in registers)
        #pragma unroll
        for (int nt = 0; nt < 2; ++nt) {
            int d = nt * 32 + l31;
            float bb  = b1[d];
            float wwx = w2[d];
            #pragma unroll
            for (int r = 0; r < 16; ++r) {
                int row = w * 32 + 4 * lh + (r & 3) + 8 * (r >> 2);
                As[row * PAD + d] = f2bf((accx[nt][r] + bb) * wwx);
                Bs[row * PAD + d] = f2bf(accy[nt][r] + bb);
            }
        }
    }
    __syncthreads();

    // ---- score: 128x128 tile, 4 waves (2x2), 2x2 accs of 32x32x16 MFMA ----
    const int wrow = (w >> 1) * 64;
    const int wcol = (w & 1) * 64;

    f32x16 acc[2][2] = {};

    #pragma unroll
    for (int kk = 0; kk < 4; ++kk) {
        int k0 = kk * 16 + lh * 8;
        bf16x8 a0 = *(const bf16x8*)&As[(wrow +      l31) * PAD + k0];
        bf16x8 a1 = *(const bf16x8*)&As[(wrow + 32 + l31) * PAD + k0];
        bf16x8 b0 = *(const bf16x8*)&Bs[(wcol +      l31) * PAD + k0];
        bf16x8 b1v = *(const bf16x8*)&Bs[(wcol + 32 + l31) * PAD + k0];
        acc[0][0] = __builtin_amdgcn_mfma_f32_32x32x16_bf16(a0, b0,  acc[0][0], 0, 0, 0);
        acc[0][1] = __builtin_amdgcn_mfma_f32_32x32x16_bf16(a0, b1v, acc[0][1], 0, 0, 0);
        acc[1][0] = __builtin_amdgcn_mfma_f32_32x32x16_bf16(a1, b0,  acc[1][0], 0, 0, 0);
        acc[1][1] = __builtin_amdgcn_mfma_f32_32x32x16_bf16(a1, b1v, acc[1][1], 0, 0, 0);
    }

    const float b2 = b2p[0];
    float* obase = out + (size_t)bh * L * L;

    #pragma unroll
    for (int ti = 0; ti < 2; ++ti) {
        #pragma unroll
        for (int tj = 0; tj < 2; ++tj) {
            int gj = j0 + wcol + tj * 32 + l31;
            #pragma unroll
            for (int r = 0; r < 16; ++r) {
                int gi = i0 + wrow + ti * 32 + 4 * lh + (r & 3) + 8 * (r >> 2);
                float v = acc[ti][tj][r] + b2;
                v = v > 0.0f ? v : 0.0f;
                obase[(size_t)gi * L + gj] = v;
            }
        }
    }
}

extern "C" void kernel_launch(void* const* d_in, const int* in_sizes, int n_in,
                              void* d_out, int out_size, void* d_ws, size_t ws_size,
                              hipStream_t stream) {
    (void)in_sizes; (void)n_in; (void)out_size; (void)d_ws; (void)ws_size;
    const float* X  = (const float*)d_in[0];
    const float* Y  = (const float*)d_in[1];
    const float* W1 = (const float*)d_in[2];
    const float* b1 = (const float*)d_in[3];
    const float* w2 = (const float*)d_in[4];
    const float* b2 = (const float*)d_in[5];
    float* out = (float*)d_out;

    dim3 grid(8, 8, BH);   // j-tiles, i-tiles, bh
    fused_kernel<<<grid, 256, 0, stream>>>(X, Y, W1, b1, w2, b2, out);
}

// Round 2
// 164.610 us; speedup vs baseline: 1.0383x; 1.0383x over previous
//
#include <hip/hip_runtime.h>

#define BH 32
#define L  1024
#define D  64

typedef short  short8  __attribute__((ext_vector_type(8)));
typedef __bf16 bf16x8  __attribute__((ext_vector_type(8)));
typedef float  f32x16  __attribute__((ext_vector_type(16)));
typedef unsigned short us4 __attribute__((ext_vector_type(4)));

__device__ __forceinline__ unsigned short f2bf(float f) {
    union { float f; unsigned u; } v; v.f = f;
    unsigned r = v.u + 0x7fffu + ((v.u >> 16) & 1u);   // RNE
    return (unsigned short)(r >> 16);
}

// ---------------------------------------------------------------------------
// Kernel 1: projections.  Xs = (X @ W1^T + b1) * w2 ; Yf = (Y @ W1^T + b1)
// stored bf16 in workspace.  blockIdx.y selects X vs Y; block does 128 rows.
// ---------------------------------------------------------------------------
__global__ __launch_bounds__(256, 4) void proj_kernel(
    const float* __restrict__ X, const float* __restrict__ Y,
    const float* __restrict__ W1, const float* __restrict__ b1,
    const float* __restrict__ w2,
    unsigned short* __restrict__ Xs, unsigned short* __restrict__ Yf)
{
    __shared__ unsigned short Wl[64 * 72];    // W1 bf16, row-major, pad 72
    __shared__ unsigned short Al[128 * 72];   // 128 input rows bf16, pad 72

    const int tid = threadIdx.x;
    const bool isX = (blockIdx.y == 0);
    const float* src = isX ? X : Y;
    unsigned short* dst = isX ? Xs : Yf;
    const int r0 = blockIdx.x * 128;          // global row (bh*L + i)

    // stage W1 (64x64 fp32) -> bf16 LDS
    {
        const int d  = tid >> 2;
        const int kb = (tid & 3) * 16;
        const float4* wp = (const float4*)(W1 + d * 64 + kb);
        #pragma unroll
        for (int q = 0; q < 4; ++q) {
            float4 v = wp[q];
            us4 t = { f2bf(v.x), f2bf(v.y), f2bf(v.z), f2bf(v.w) };
            *(us4*)&Wl[d * 72 + kb + q * 4] = t;
        }
    }
    // stage 128 rows of X/Y (contiguous 32 KB) -> bf16 LDS
    {
        const float4* xp = (const float4*)(src + (size_t)r0 * 64);
        #pragma unroll
        for (int p = 0; p < 8; ++p) {
            int c = tid + 256 * p;            // float4 chunk 0..2047
            float4 v = xp[c];
            int row = c >> 4;                 // 16 float4 per 64-elem row
            int c4  = (c & 15) * 4;
            us4 t = { f2bf(v.x), f2bf(v.y), f2bf(v.z), f2bf(v.w) };
            *(us4*)&Al[row * 72 + c4] = t;
        }
    }
    __syncthreads();

    const int w   = tid >> 6;                 // wave 0..3 -> rows w*32..+31
    const int l   = tid & 63;
    const int l31 = l & 31;
    const int lh  = l >> 5;

    f32x16 acc[2] = {};

    const int arow = w * 32 + l31;
    #pragma unroll
    for (int kk = 0; kk < 4; ++kk) {
        int k0 = kk * 16 + lh * 8;
        bf16x8 a = *(const bf16x8*)&Al[arow * 72 + k0];
        #pragma unroll
        for (int nt = 0; nt < 2; ++nt) {
            bf16x8 b = *(const bf16x8*)&Wl[(nt * 32 + l31) * 72 + k0];
            acc[nt] = __builtin_amdgcn_mfma_f32_32x32x16_bf16(a, b, acc[nt], 0, 0, 0);
        }
    }

    #pragma unroll
    for (int nt = 0; nt < 2; ++nt) {
        int d = nt * 32 + l31;
        float bb = b1[d];
        float ww = isX ? w2[d] : 1.0f;
        #pragma unroll
        for (int r = 0; r < 16; ++r) {
            int row = w * 32 + 4 * lh + (r & 3) + 8 * (r >> 2);
            float v = (acc[nt][r] + bb) * ww;
            dst[(size_t)(r0 + row) * 64 + d] = f2bf(v);
        }
    }
}

// ---------------------------------------------------------------------------
// Kernel 2: per-bh score, full-width panels.  C = relu(Xs @ Yf^T + b2).
// Block = 128 rows x 1024 cols of one bh.  grid (32 bh, 8 i) = 256 blocks,
// 1 block/CU, 512 threads (8 waves, 2x4 wave grid).
// Bs = entire 1024x64 Yf panel in LDS, XOR-swizzled 16B slots (unpadded
// 128 B rows would be a 32-way bank conflict on the b-fragment reads).
// Each block writes one contiguous 512 KiB output stream.
// ---------------------------------------------------------------------------
__global__ __launch_bounds__(512, 2) void score_kernel(
    const unsigned short* __restrict__ Xs, const unsigned short* __restrict__ Yf,
    const float* __restrict__ b2p, float* __restrict__ out)
{
    __shared__ unsigned short As[128 * 72];    // 18 KiB, pad-72
    __shared__ unsigned short Bs[1024 * 64];   // 128 KiB, swizzled slots

    const int tid = threadIdx.x;
    const int bh  = blockIdx.x;                // same-bh blocks share an XCD
    const int i0  = blockIdx.y * 128;

    const unsigned short* aSrc = Xs + ((size_t)bh * L + i0) * D;  // 16 KiB
    const unsigned short* bSrc = Yf + (size_t)bh * L * D;         // 128 KiB

    // stage As (128x64, pad-72, linear slots)
    #pragma unroll
    for (int p = 0; p < 2; ++p) {
        int c   = tid + 512 * p;              // 16B chunk 0..1023
        int row = c >> 3;
        int sl  = c & 7;
        *(short8*)&As[row * 72 + sl * 8] = *(const short8*)(aSrc + (size_t)c * 8);
    }
    // stage Bs (1024x64, slot ^= row&7)
    #pragma unroll
    for (int p = 0; p < 16; ++p) {
        int c   = tid + 512 * p;              // 16B chunk 0..8191
        int row = c >> 3;
        int sl  = (c & 7) ^ (row & 7);
        *(short8*)&Bs[row * 64 + sl * 8] = *(const short8*)(bSrc + (size_t)c * 8);
    }
    __syncthreads();

    const int w   = tid >> 6;                 // wave 0..7
    const int l   = tid & 63;
    const int l31 = l & 31;
    const int lh  = l >> 5;
    const int wr  = w & 1;                    // row half: 64 rows
    const int wc  = w >> 1;                   // col quarter: 256 cols

    const float b2 = b2p[0];
    float* obase = out + ((size_t)bh * L + i0) * L;
    const int xsl = l31 & 7;                  // swizzle term for b reads

    #pragma unroll
    for (int cc = 0; cc < 2; ++cc) {          // two 128-col chunks per wave
        f32x16 acc[2][4] = {};
        const int jbase = wc * 256 + cc * 128;

        #pragma unroll
        for (int kk = 0; kk < 4; ++kk) {
            int k0 = kk * 16 + lh * 8;
            bf16x8 a0 = *(const bf16x8*)&As[(wr * 64 +      l31) * 72 + k0];
            bf16x8 a1 = *(const bf16x8*)&As[(wr * 64 + 32 + l31) * 72 + k0];
            int slot = kk * 2 + lh;
            #pragma unroll
            for (int tj = 0; tj < 4; ++tj) {
                int j = jbase + tj * 32 + l31;
                bf16x8 b = *(const bf16x8*)&Bs[j * 64 + ((slot ^ xsl) * 8)];
                acc[0][tj] = __builtin_amdgcn_mfma_f32_32x32x16_bf16(a0, b, acc[0][tj], 0, 0, 0);
                acc[1][tj] = __builtin_amdgcn_mfma_f32_32x32x16_bf16(a1, b, acc[1][tj], 0, 0, 0);
            }
        }

        #pragma unroll
        for (int si = 0; si < 2; ++si) {
            #pragma unroll
            for (int r = 0; r < 16; ++r) {
                int gi = wr * 64 + si * 32 + 4 * lh + (r & 3) + 8 * (r >> 2);
                float* rowp = obase + (size_t)gi * L + jbase + l31;
                #pragma unroll
                for (int tj = 0; tj < 4; ++tj) {
                    float v = acc[si][tj][r] + b2;
                    v = v > 0.0f ? v : 0.0f;
                    rowp[tj * 32] = v;
                }
            }
        }
    }
}

extern "C" void kernel_launch(void* const* d_in, const int* in_sizes, int n_in,
                              void* d_out, int out_size, void* d_ws, size_t ws_size,
                              hipStream_t stream) {
    (void)in_sizes; (void)n_in; (void)out_size; (void)ws_size;
    const float* X  = (const float*)d_in[0];
    const float* Y  = (const float*)d_in[1];
    const float* W1 = (const float*)d_in[2];
    const float* b1 = (const float*)d_in[3];
    const float* w2 = (const float*)d_in[4];
    const float* b2 = (const float*)d_in[5];
    float* out = (float*)d_out;

    unsigned short* Xs = (unsigned short*)d_ws;               // 4 MB bf16
    unsigned short* Yf = Xs + (size_t)BH * L * D;             // + 4 MB

    dim3 pgrid(256, 2, 1);
    proj_kernel<<<pgrid, 256, 0, stream>>>(X, Y, W1, b1, w2, Xs, Yf);

    dim3 sgrid(32, 8, 1);                                     // bh, i-tiles
    score_kernel<<<sgrid, 512, 0, stream>>>(Xs, Yf, b2, out);
}

// Round 3
// 163.265 us; speedup vs baseline: 1.0469x; 1.0082x over previous
//
#include <hip/hip_runtime.h>

#define BH 32
#define L  1024
#define D  64

typedef short  short8  __attribute__((ext_vector_type(8)));
typedef __bf16 bf16x8  __attribute__((ext_vector_type(8)));
typedef float  f32x16  __attribute__((ext_vector_type(16)));
typedef unsigned short us4 __attribute__((ext_vector_type(4)));

__device__ __forceinline__ unsigned short f2bf(float f) {
    union { float f; unsigned u; } v; v.f = f;
    unsigned r = v.u + 0x7fffu + ((v.u >> 16) & 1u);   // RNE
    return (unsigned short)(r >> 16);
}

// ---------------------------------------------------------------------------
// Kernel 1: projections.  Xs = (X @ W1^T + b1) * w2 ; Yf = (Y @ W1^T + b1)
// stored bf16 in workspace.  blockIdx.y selects X vs Y; block does 128 rows.
// ---------------------------------------------------------------------------
__global__ __launch_bounds__(256, 4) void proj_kernel(
    const float* __restrict__ X, const float* __restrict__ Y,
    const float* __restrict__ W1, const float* __restrict__ b1,
    const float* __restrict__ w2,
    unsigned short* __restrict__ Xs, unsigned short* __restrict__ Yf)
{
    __shared__ unsigned short Wl[64 * 72];    // W1 bf16, row-major, pad 72
    __shared__ unsigned short Al[128 * 72];   // 128 input rows bf16, pad 72

    const int tid = threadIdx.x;
    const bool isX = (blockIdx.y == 0);
    const float* src = isX ? X : Y;
    unsigned short* dst = isX ? Xs : Yf;
    const int r0 = blockIdx.x * 128;          // global row (bh*L + i)

    // stage W1 (64x64 fp32) -> bf16 LDS
    {
        const int d  = tid >> 2;
        const int kb = (tid & 3) * 16;
        const float4* wp = (const float4*)(W1 + d * 64 + kb);
        #pragma unroll
        for (int q = 0; q < 4; ++q) {
            float4 v = wp[q];
            us4 t = { f2bf(v.x), f2bf(v.y), f2bf(v.z), f2bf(v.w) };
            *(us4*)&Wl[d * 72 + kb + q * 4] = t;
        }
    }
    // stage 128 rows of X/Y (contiguous 32 KB) -> bf16 LDS
    {
        const float4* xp = (const float4*)(src + (size_t)r0 * 64);
        #pragma unroll
        for (int p = 0; p < 8; ++p) {
            int c = tid + 256 * p;            // float4 chunk 0..2047
            float4 v = xp[c];
            int row = c >> 4;                 // 16 float4 per 64-elem row
            int c4  = (c & 15) * 4;
            us4 t = { f2bf(v.x), f2bf(v.y), f2bf(v.z), f2bf(v.w) };
            *(us4*)&Al[row * 72 + c4] = t;
        }
    }
    __syncthreads();

    const int w   = tid >> 6;                 // wave 0..3 -> rows w*32..+31
    const int l   = tid & 63;
    const int l31 = l & 31;
    const int lh  = l >> 5;

    f32x16 acc[2] = {};

    const int arow = w * 32 + l31;
    #pragma unroll
    for (int kk = 0; kk < 4; ++kk) {
        int k0 = kk * 16 + lh * 8;
        bf16x8 a = *(const bf16x8*)&Al[arow * 72 + k0];
        #pragma unroll
        for (int nt = 0; nt < 2; ++nt) {
            bf16x8 b = *(const bf16x8*)&Wl[(nt * 32 + l31) * 72 + k0];
            acc[nt] = __builtin_amdgcn_mfma_f32_32x32x16_bf16(a, b, acc[nt], 0, 0, 0);
        }
    }

    #pragma unroll
    for (int nt = 0; nt < 2; ++nt) {
        int d = nt * 32 + l31;
        float bb = b1[d];
        float ww = isX ? w2[d] : 1.0f;
        #pragma unroll
        for (int r = 0; r < 16; ++r) {
            int row = w * 32 + 4 * lh + (r & 3) + 8 * (r >> 2);
            float v = (acc[nt][r] + bb) * ww;
            dst[(size_t)(r0 + row) * 64 + d] = f2bf(v);
        }
    }
}

// ---------------------------------------------------------------------------
// Kernel 2: per-bh TN GEMM, C = relu(Xs @ Yf^T + b2), M=N=1024, K=64.
// 128x128 block tile, 4 waves (2x2), each wave 2x2 accs of 32x32x16 MFMA.
// Epilogue: transpose acc through LDS (reuse As) so global stores are
// float4/lane, 1 KiB contiguous per wave-instr (the fill's pattern), in
// ascending address order per block.
// ---------------------------------------------------------------------------
__global__ __launch_bounds__(256, 4) void score_kernel(
    const unsigned short* __restrict__ Xs, const unsigned short* __restrict__ Yf,
    const float* __restrict__ b2p, float* __restrict__ out)
{
    __shared__ alignas(16) unsigned short As[128 * 72];   // 18 KiB (also fp32 stage)
    __shared__ unsigned short Bs[128 * 72];               // 18 KiB

    const int tid = threadIdx.x;
    const int bh  = blockIdx.z;
    const int i0  = blockIdx.y * 128;
    const int j0  = blockIdx.x * 128;

    const unsigned short* aSrc = Xs + ((size_t)bh * L + i0) * D;  // 16 KiB
    const unsigned short* bSrc = Yf + ((size_t)bh * L + j0) * D;

    #pragma unroll
    for (int p = 0; p < 4; ++p) {
        int c   = tid + 256 * p;             // 16B chunk 0..1023
        int row = c >> 3;
        int col = c & 7;
        short8 va = *(const short8*)(aSrc + (size_t)c * 8);
        short8 vb = *(const short8*)(bSrc + (size_t)c * 8);
        *(short8*)&As[row * 72 + col * 8] = va;
        *(short8*)&Bs[row * 72 + col * 8] = vb;
    }
    __syncthreads();

    const int w    = tid >> 6;
    const int l    = tid & 63;
    const int l31  = l & 31;
    const int lh   = l >> 5;
    const int wrow = (w >> 1) * 64;
    const int wcol = (w & 1) * 64;

    f32x16 acc[2][2] = {};

    #pragma unroll
    for (int kk = 0; kk < 4; ++kk) {
        int k0 = kk * 16 + lh * 8;
        bf16x8 a0 = *(const bf16x8*)&As[(wrow +      l31) * 72 + k0];
        bf16x8 a1 = *(const bf16x8*)&As[(wrow + 32 + l31) * 72 + k0];
        bf16x8 b0 = *(const bf16x8*)&Bs[(wcol +      l31) * 72 + k0];
        bf16x8 b1v = *(const bf16x8*)&Bs[(wcol + 32 + l31) * 72 + k0];
        acc[0][0] = __builtin_amdgcn_mfma_f32_32x32x16_bf16(a0, b0,  acc[0][0], 0, 0, 0);
        acc[0][1] = __builtin_amdgcn_mfma_f32_32x32x16_bf16(a0, b1v, acc[0][1], 0, 0, 0);
        acc[1][0] = __builtin_amdgcn_mfma_f32_32x32x16_bf16(a1, b0,  acc[1][0], 0, 0, 0);
        acc[1][1] = __builtin_amdgcn_mfma_f32_32x32x16_bf16(a1, b1v, acc[1][1], 0, 0, 0);
    }

    __syncthreads();                          // all As/Bs reads done before reuse

    const float b2 = b2p[0];
    float* obase = out + ((size_t)bh * L + i0) * L + j0;
    float* stage = (float*)As;                // 32x128 fp32 = 16 KiB

    #pragma unroll
    for (int chunk = 0; chunk < 4; ++chunk) {
        // chunk covers block-local rows [chunk*32, chunk*32+32)
        // those rows live in acc[ti][*] of waves with wrow == (chunk>>1)*64,
        // ti == chunk & 1
        if ((w >> 1) == (chunk >> 1)) {
            const int ti = chunk & 1;
            #pragma unroll
            for (int tj = 0; tj < 2; ++tj) {
                #pragma unroll
                for (int r = 0; r < 16; ++r) {
                    int lr = 4 * lh + (r & 3) + 8 * (r >> 2);   // 0..31
                    int lc = wcol + tj * 32 + l31;              // 0..127
                    float v = acc[ti][tj][r] + b2;
                    v = v > 0.0f ? v : 0.0f;
                    stage[lr * 128 + lc] = v;
                }
            }
        }
        __syncthreads();
        // store 32 rows x 128 cols = 16 KiB, float4/lane, ascending addresses
        const float4* sp = (const float4*)stage;
        const int rbase = chunk * 32;
        #pragma unroll
        for (int q = 0; q < 4; ++q) {
            int idx  = tid + 256 * q;        // float4 index 0..1023
            float4 v = sp[idx];
            int lrow = rbase + (idx >> 5);   // 32 float4 per 128-col row
            int lcol = (idx & 31) << 2;
            *(float4*)&obase[(size_t)lrow * L + lcol] = v;
        }
        __syncthreads();
    }
}

extern "C" void kernel_launch(void* const* d_in, const int* in_sizes, int n_in,
                              void* d_out, int out_size, void* d_ws, size_t ws_size,
                              hipStream_t stream) {
    (void)in_sizes; (void)n_in; (void)out_size; (void)ws_size;
    const float* X  = (const float*)d_in[0];
    const float* Y  = (const float*)d_in[1];
    const float* W1 = (const float*)d_in[2];
    const float* b1 = (const float*)d_in[3];
    const float* w2 = (const float*)d_in[4];
    const float* b2 = (const float*)d_in[5];
    float* out = (float*)d_out;

    unsigned short* Xs = (unsigned short*)d_ws;               // 4 MB bf16
    unsigned short* Yf = Xs + (size_t)BH * L * D;             // + 4 MB

    dim3 pgrid(256, 2, 1);
    proj_kernel<<<pgrid, 256, 0, stream>>>(X, Y, W1, b1, w2, Xs, Yf);

    dim3 ggrid(8, 8, BH);                                     // j-tiles, i-tiles, bh
    score_kernel<<<ggrid, 256, 0, stream>>>(Xs, Yf, b2, out);
}

// Round 4
// 163.024 us; speedup vs baseline: 1.0484x; 1.0015x over previous
//
#include <hip/hip_runtime.h>

#define BH 32
#define L  1024
#define D  64

typedef short  short8  __attribute__((ext_vector_type(8)));
typedef __bf16 bf16x8  __attribute__((ext_vector_type(8)));
typedef float  f32x16  __attribute__((ext_vector_type(16)));
typedef unsigned short us4 __attribute__((ext_vector_type(4)));

__device__ __forceinline__ unsigned short f2bf(float f) {
    union { float f; unsigned u; } v; v.f = f;
    unsigned r = v.u + 0x7fffu + ((v.u >> 16) & 1u);   // RNE
    return (unsigned short)(r >> 16);
}

// ---------------------------------------------------------------------------
// Kernel 1: projections.  Xs = (X @ W1^T + b1) * w2 ; Yf = (Y @ W1^T + b1)
// stored bf16 in workspace.  blockIdx.y selects X vs Y; block does 128 rows.
// ---------------------------------------------------------------------------
__global__ __launch_bounds__(256, 4) void proj_kernel(
    const float* __restrict__ X, const float* __restrict__ Y,
    const float* __restrict__ W1, const float* __restrict__ b1,
    const float* __restrict__ w2,
    unsigned short* __restrict__ Xs, unsigned short* __restrict__ Yf)
{
    __shared__ unsigned short Wl[64 * 72];    // W1 bf16, row-major, pad 72
    __shared__ unsigned short Al[128 * 72];   // 128 input rows bf16, pad 72

    const int tid = threadIdx.x;
    const bool isX = (blockIdx.y == 0);
    const float* src = isX ? X : Y;
    unsigned short* dst = isX ? Xs : Yf;
    const int r0 = blockIdx.x * 128;          // global row (bh*L + i)

    // stage W1 (64x64 fp32) -> bf16 LDS
    {
        const int d  = tid >> 2;
        const int kb = (tid & 3) * 16;
        const float4* wp = (const float4*)(W1 + d * 64 + kb);
        #pragma unroll
        for (int q = 0; q < 4; ++q) {
            float4 v = wp[q];
            us4 t = { f2bf(v.x), f2bf(v.y), f2bf(v.z), f2bf(v.w) };
            *(us4*)&Wl[d * 72 + kb + q * 4] = t;
        }
    }
    // stage 128 rows of X/Y (contiguous 32 KB) -> bf16 LDS
    {
        const float4* xp = (const float4*)(src + (size_t)r0 * 64);
        #pragma unroll
        for (int p = 0; p < 8; ++p) {
            int c = tid + 256 * p;            // float4 chunk 0..2047
            float4 v = xp[c];
            int row = c >> 4;                 // 16 float4 per 64-elem row
            int c4  = (c & 15) * 4;
            us4 t = { f2bf(v.x), f2bf(v.y), f2bf(v.z), f2bf(v.w) };
            *(us4*)&Al[row * 72 + c4] = t;
        }
    }
    __syncthreads();

    const int w   = tid >> 6;                 // wave 0..3 -> rows w*32..+31
    const int l   = tid & 63;
    const int l31 = l & 31;
    const int lh  = l >> 5;

    f32x16 acc[2] = {};

    const int arow = w * 32 + l31;
    #pragma unroll
    for (int kk = 0; kk < 4; ++kk) {
        int k0 = kk * 16 + lh * 8;
        bf16x8 a = *(const bf16x8*)&Al[arow * 72 + k0];
        #pragma unroll
        for (int nt = 0; nt < 2; ++nt) {
            bf16x8 b = *(const bf16x8*)&Wl[(nt * 32 + l31) * 72 + k0];
            acc[nt] = __builtin_amdgcn_mfma_f32_32x32x16_bf16(a, b, acc[nt], 0, 0, 0);
        }
    }

    #pragma unroll
    for (int nt = 0; nt < 2; ++nt) {
        int d = nt * 32 + l31;
        float bb = b1[d];
        float ww = isX ? w2[d] : 1.0f;
        #pragma unroll
        for (int r = 0; r < 16; ++r) {
            int row = w * 32 + 4 * lh + (r & 3) + 8 * (r >> 2);
            float v = (acc[nt][r] + bb) * ww;
            dst[(size_t)(r0 + row) * 64 + d] = f2bf(v);
        }
    }
}

// ---------------------------------------------------------------------------
// Kernel 2: per-bh TN GEMM, C = relu(Xs @ Yf^T + b2), M=N=1024, K=64.
// 128x128 block tile, 4 waves (2x2), each wave 2x2 accs of 32x32x16 MFMA.
// Output stores are NONTEMPORAL (nt): the 128 MiB fp32 out stream is
// write-once; nt avoids L2 write-allocate thrash of the Xs/Yf panels.
// ---------------------------------------------------------------------------
__global__ __launch_bounds__(256, 4) void score_kernel(
    const unsigned short* __restrict__ Xs, const unsigned short* __restrict__ Yf,
    const float* __restrict__ b2p, float* __restrict__ out)
{
    __shared__ unsigned short As[128 * 72];
    __shared__ unsigned short Bs[128 * 72];

    const int tid = threadIdx.x;
    const int bh  = blockIdx.z;
    const int i0  = blockIdx.y * 128;
    const int j0  = blockIdx.x * 128;

    const unsigned short* aSrc = Xs + ((size_t)bh * L + i0) * D;  // 16 KB contiguous
    const unsigned short* bSrc = Yf + ((size_t)bh * L + j0) * D;

    // stage both 128x64 bf16 tiles (each contiguous 16 KB) into padded LDS
    #pragma unroll
    for (int p = 0; p < 4; ++p) {
        int c   = tid + 256 * p;             // 16B chunk 0..1023
        int row = c >> 3;                    // 8 chunks per 64-elem row
        int col = c & 7;
        short8 va = *(const short8*)(aSrc + (size_t)c * 8);
        short8 vb = *(const short8*)(bSrc + (size_t)c * 8);
        *(short8*)&As[row * 72 + col * 8] = va;
        *(short8*)&Bs[row * 72 + col * 8] = vb;
    }
    __syncthreads();

    const int w    = tid >> 6;
    const int l    = tid & 63;
    const int l31  = l & 31;
    const int lh   = l >> 5;
    const int wrow = (w >> 1) * 64;
    const int wcol = (w & 1) * 64;

    f32x16 acc[2][2] = {};

    #pragma unroll
    for (int kk = 0; kk < 4; ++kk) {
        int k0 = kk * 16 + lh * 8;
        bf16x8 a0 = *(const bf16x8*)&As[(wrow +      l31) * 72 + k0];
        bf16x8 a1 = *(const bf16x8*)&As[(wrow + 32 + l31) * 72 + k0];
        bf16x8 b0 = *(const bf16x8*)&Bs[(wcol +      l31) * 72 + k0];
        bf16x8 b1v = *(const bf16x8*)&Bs[(wcol + 32 + l31) * 72 + k0];
        acc[0][0] = __builtin_amdgcn_mfma_f32_32x32x16_bf16(a0, b0,  acc[0][0], 0, 0, 0);
        acc[0][1] = __builtin_amdgcn_mfma_f32_32x32x16_bf16(a0, b1v, acc[0][1], 0, 0, 0);
        acc[1][0] = __builtin_amdgcn_mfma_f32_32x32x16_bf16(a1, b0,  acc[1][0], 0, 0, 0);
        acc[1][1] = __builtin_amdgcn_mfma_f32_32x32x16_bf16(a1, b1v, acc[1][1], 0, 0, 0);
    }

    const float b2 = b2p[0];
    float* obase = out + (size_t)bh * L * L;

    #pragma unroll
    for (int ti = 0; ti < 2; ++ti) {
        #pragma unroll
        for (int tj = 0; tj < 2; ++tj) {
            int gj = j0 + wcol + tj * 32 + l31;
            #pragma unroll
            for (int r = 0; r < 16; ++r) {
                int gi = i0 + wrow + ti * 32 + 4 * lh + (r & 3) + 8 * (r >> 2);
                float v = acc[ti][tj][r] + b2;
                v = v > 0.0f ? v : 0.0f;
                __builtin_nontemporal_store(v, &obase[(size_t)gi * L + gj]);
            }
        }
    }
}

extern "C" void kernel_launch(void* const* d_in, const int* in_sizes, int n_in,
                              void* d_out, int out_size, void* d_ws, size_t ws_size,
                              hipStream_t stream) {
    (void)in_sizes; (void)n_in; (void)out_size; (void)ws_size;
    const float* X  = (const float*)d_in[0];
    const float* Y  = (const float*)d_in[1];
    const float* W1 = (const float*)d_in[2];
    const float* b1 = (const float*)d_in[3];
    const float* w2 = (const float*)d_in[4];
    const float* b2 = (const float*)d_in[5];
    float* out = (float*)d_out;

    unsigned short* Xs = (unsigned short*)d_ws;               // 4 MB bf16
    unsigned short* Yf = Xs + (size_t)BH * L * D;             // + 4 MB

    dim3 pgrid(256, 2, 1);
    proj_kernel<<<pgrid, 256, 0, stream>>>(X, Y, W1, b1, w2, Xs, Yf);

    dim3 ggrid(8, 8, BH);                                     // j-tiles, i-tiles, bh
    score_kernel<<<ggrid, 256, 0, stream>>>(Xs, Yf, b2, out);
}